// Round 1
// baseline (1522.884 us; speedup 1.0000x reference)
//
#include <hip/hip_runtime.h>
#include <stdint.h>

// Problem constants (fixed by setup_inputs)
#define QN 512
#define DIM 768
#define NLIB 262144
#define BK 32
#define NB 128                    // columns (lib rows) per block
#define NBLOCKS (NLIB / NB)       // 2048
#define KSTEPS (DIM / BK)         // 24
#define INF_F 1.0e30f

typedef _Float16 half8 __attribute__((ext_vector_type(8)));
typedef float floatx16 __attribute__((ext_vector_type(16)));
typedef float f32x4 __attribute__((ext_vector_type(4)));
typedef int i32x4 __attribute__((ext_vector_type(4)));

#define GLOBAL_TO_LDS16(g, l)                                                  \
  __builtin_amdgcn_global_load_lds(                                            \
      (const __attribute__((address_space(1))) unsigned*)(g),                  \
      (__attribute__((address_space(3))) unsigned*)(l), 16, 0, 0)

// ---------------------------------------------------------------------------
// Kernel 1: convert query fp32 -> fp16, pre-tiled per K-step and pre-swizzled
// so the GEMM can stage it with flat global_load_lds (wave-uniform base +
// lane*16). Layout: ws block per kstep = 512 rows x 4 chunks(16B); chunk c of
// row m stored at slot (m*4 + (c ^ ((m>>1)&3))).
// ---------------------------------------------------------------------------
__global__ void prep_A(const float* __restrict__ query,
                       _Float16* __restrict__ A_ws) {
  int tid = blockIdx.x * blockDim.x + threadIdx.x;
  if (tid >= KSTEPS * QN * 4) return;
  int c = tid & 3;
  int m = (tid >> 2) & (QN - 1);
  int ks = tid >> 11;
  const float* src = query + (size_t)m * DIM + ks * BK + c * 8;
  half8 h;
#pragma unroll
  for (int i = 0; i < 8; ++i) h[i] = (_Float16)src[i];
  int cp = c ^ ((m >> 1) & 3);
  *((half8*)(A_ws + (size_t)ks * (QN * BK) + (m * 4 + cp) * 8)) = h;
}

// ---------------------------------------------------------------------------
// Kernel 2: fp16 MFMA GEMM (coarse scores s = ||x||^2 - 2 q.x) + per-query
// top-4 candidate selection per 128-column stripe.
// Block: 512 threads (8 waves), tile 512(M) x 128(N), wave tile 128x64.
// ---------------------------------------------------------------------------
__global__ __launch_bounds__(512, 2) void gemm_select(
    const float* __restrict__ lib, const _Float16* __restrict__ A_ws,
    float* __restrict__ cand_val, int* __restrict__ cand_idx) {
  __shared__ union {
    struct {
      alignas(16) _Float16 A[QN * BK];   // 32 KB, swizzled
      alignas(16) _Float16 B[NB * BK];   //  8 KB, swizzled
    } stage;
    float S[64 * 132];                   // epilogue score chunk (33 KB)
  } u;
  __shared__ float candv[64 * 8 * 3];
  __shared__ int candi[64 * 8 * 3];
  __shared__ float xsq_part[512];
  __shared__ float xsq[NB];

  const int tid = threadIdx.x;
  const int wave = tid >> 6;
  const int lane = tid & 63;
  const int rr = lane & 31;
  const int half = lane >> 5;
  const int swz = (rr >> 1) & 3;
  const int wm = wave >> 1;  // 0..3  (M group of 128 rows)
  const int wn = wave & 1;   // 0..1  (N group of 64 cols)
  const int nbase = blockIdx.x * NB;

  // B staging mapping: thread -> (column bn, k-chunk bc)
  const int bn = tid >> 2;  // 0..127
  const int bc = tid & 3;   // 0..3
  const float* bptr = lib + (size_t)(nbase + bn) * DIM + bc * 8;
  const int bslot = (bn * 4 + (bc ^ ((bn >> 1) & 3))) * 8;  // f16 index

  floatx16 acc[4][2];
#pragma unroll
  for (int t = 0; t < 4; ++t)
#pragma unroll
    for (int j = 0; j < 2; ++j)
#pragma unroll
      for (int r = 0; r < 16; ++r) acc[t][j][r] = 0.0f;

  float xacc = 0.0f;
  f32x4 b0 = *(const f32x4*)(bptr);
  f32x4 b1 = *(const f32x4*)(bptr + 4);

  for (int ks = 0; ks < KSTEPS; ++ks) {
    __syncthreads();  // previous compute done; LDS reusable
    // --- stage A: async 32 KB flat copy (pre-swizzled in ws) ---
    {
      const _Float16* gA = A_ws + (size_t)ks * (QN * BK) + wave * 2048 + lane * 8;
      _Float16* lA = u.stage.A + wave * 2048;  // wave-uniform LDS base
#pragma unroll
      for (int i = 0; i < 4; ++i) GLOBAL_TO_LDS16(gA + i * 512, lA + i * 512);
    }
    // --- stage B: convert current regs, accumulate ||x||^2 partials ---
    {
      half8 h;
#pragma unroll
      for (int i = 0; i < 4; ++i) {
        h[i] = (_Float16)b0[i];
        h[4 + i] = (_Float16)b1[i];
        xacc += b0[i] * b0[i] + b1[i] * b1[i];
      }
      *((half8*)&u.stage.B[bslot]) = h;
    }
    __syncthreads();
    // --- prefetch next iter's B into regs (overlaps with MFMA below) ---
    if (ks + 1 < KSTEPS) {
      b0 = *(const f32x4*)(bptr + (ks + 1) * BK);
      b1 = *(const f32x4*)(bptr + (ks + 1) * BK + 4);
    }
    // --- compute: 2 substeps of K=16, 8 MFMA each ---
#pragma unroll
    for (int s = 0; s < 2; ++s) {
      const int cc = (2 * s + half) ^ swz;
      half8 bf0 = *((half8*)&u.stage.B[((wn * 64 + rr) * 4 + cc) * 8]);
      half8 bf1 = *((half8*)&u.stage.B[((wn * 64 + 32 + rr) * 4 + cc) * 8]);
#pragma unroll
      for (int t = 0; t < 4; ++t) {
        half8 af =
            *((half8*)&u.stage.A[((wm * 128 + t * 32 + rr) * 4 + cc) * 8]);
        acc[t][0] =
            __builtin_amdgcn_mfma_f32_32x32x16_f16(af, bf0, acc[t][0], 0, 0, 0);
        acc[t][1] =
            __builtin_amdgcn_mfma_f32_32x32x16_f16(af, bf1, acc[t][1], 0, 0, 0);
      }
    }
  }

  // --- reduce ||x||^2 partials (4 threads per column) ---
  xsq_part[tid] = xacc;
  __syncthreads();
  if (tid < NB)
    xsq[tid] = xsq_part[tid * 4] + xsq_part[tid * 4 + 1] +
               xsq_part[tid * 4 + 2] + xsq_part[tid * 4 + 3];
  __syncthreads();
  float xsqv[2];
  xsqv[0] = xsq[wn * 64 + rr];
  xsqv[1] = xsq[wn * 64 + 32 + rr];

  // --- epilogue: 8 chunks of 64 queries; per-query top-4 of this stripe ---
#pragma unroll
  for (int qc = 0; qc < 8; ++qc) {
    if (wm == (qc >> 1)) {
      const int hh = qc & 1;
#pragma unroll
      for (int ti = 0; ti < 2; ++ti) {
        const int t = 2 * hh + ti;
#pragma unroll
        for (int j = 0; j < 2; ++j) {
          const int col = wn * 64 + j * 32 + rr;
#pragma unroll
          for (int r = 0; r < 16; ++r) {
            int rowin = (r & 3) + 8 * (r >> 2) + 4 * half;
            u.S[(ti * 32 + rowin) * 132 + col] =
                fmaf(-2.0f, acc[t][j][r], xsqv[j]);
          }
        }
      }
    }
    __syncthreads();
    // scan: 8 threads per query, strided columns, local top-3
    {
      const int qq = tid >> 3, uu = tid & 7;
      float v0 = INF_F, v1 = INF_F, v2 = INF_F;
      int i0 = 0, i1 = 0, i2 = 0;
#pragma unroll
      for (int i = 0; i < 16; ++i) {
        int col = uu + 8 * i;
        float v = u.S[qq * 132 + col];
        if (v < v2) {
          if (v < v1) {
            v2 = v1; i2 = i1;
            if (v < v0) { v1 = v0; i1 = i0; v0 = v; i0 = col; }
            else { v1 = v; i1 = col; }
          } else { v2 = v; i2 = col; }
        }
      }
      int base = (qq * 8 + uu) * 3;
      candv[base] = v0; candi[base] = i0;
      candv[base + 1] = v1; candi[base + 1] = i1;
      candv[base + 2] = v2; candi[base + 2] = i2;
    }
    __syncthreads();
    if (tid < 64) {  // merge 24 -> top-4, write to global candidate table
      float w0 = INF_F, w1 = INF_F, w2 = INF_F, w3 = INF_F;
      int j0 = 0, j1 = 0, j2 = 0, j3 = 0;
      for (int p = 0; p < 24; ++p) {
        float v = candv[tid * 24 + p];
        int id = candi[tid * 24 + p];
        if (v < w3) {
          if (v < w1) {
            if (v < w0) { w3 = w2; j3 = j2; w2 = w1; j2 = j1; w1 = w0; j1 = j0; w0 = v; j0 = id; }
            else { w3 = w2; j3 = j2; w2 = w1; j2 = j1; w1 = v; j1 = id; }
          } else {
            if (v < w2) { w3 = w2; j3 = j2; w2 = v; j2 = id; }
            else { w3 = v; j3 = id; }
          }
        }
      }
      int qg = qc * 64 + tid;
      size_t off = ((size_t)qg * NBLOCKS + blockIdx.x) * 4;
      f32x4 wv = {w0, w1, w2, w3};
      i32x4 wi = {nbase + j0, nbase + j1, nbase + j2, nbase + j3};
      *(f32x4*)(cand_val + off) = wv;
      *(i32x4*)(cand_idx + off) = wi;
    }
    __syncthreads();
  }
}

// ---------------------------------------------------------------------------
// Kernel 3: per query, merge 8192 candidates -> coarse top-16 -> exact fp64
// rescore -> sorted top-10 (dis + indices-as-float).
// ---------------------------------------------------------------------------
__device__ inline void insert_sorted(float* bv, int* bi, int K, float v, int id) {
  if (v > bv[K - 1] || (v == bv[K - 1] && id >= bi[K - 1])) return;
  int p = K - 1;
  while (p > 0 && (bv[p - 1] > v || (bv[p - 1] == v && bi[p - 1] > id))) {
    bv[p] = bv[p - 1]; bi[p] = bi[p - 1]; --p;
  }
  bv[p] = v; bi[p] = id;
}

__global__ __launch_bounds__(256) void merge_rescore(
    const float* __restrict__ query, const float* __restrict__ lib,
    const float* __restrict__ cand_val, const int* __restrict__ cand_idx,
    float* __restrict__ out) {
  const int q = blockIdx.x;
  const int tid = threadIdx.x;
  const int wave = tid >> 6;
  const int lane = tid & 63;
  __shared__ float lv[256 * 4];
  __shared__ int li[256 * 4];
  __shared__ float l2v[32 * 8];
  __shared__ int l2i[32 * 8];
  __shared__ int sel[16];
  __shared__ double d2_sh[16];
  __shared__ double qred[4];
  __shared__ double qsq_sh;

  const float* cv = cand_val + (size_t)q * (NBLOCKS * 4);
  const int* ci = cand_idx + (size_t)q * (NBLOCKS * 4);

  // phase 1: each thread scans 32 pairs -> top-4
  {
    float v0 = INF_F, v1 = INF_F, v2 = INF_F, v3 = INF_F;
    int i0 = 0, i1 = 0, i2 = 0, i3 = 0;
    const f32x4* cvv = (const f32x4*)(cv + tid * 32);
    const i32x4* civ = (const i32x4*)(ci + tid * 32);
#pragma unroll
    for (int p8 = 0; p8 < 8; ++p8) {
      f32x4 vv = cvv[p8];
      i32x4 ii = civ[p8];
#pragma unroll
      for (int e = 0; e < 4; ++e) {
        float v = vv[e];
        int id = ii[e];
        if (v < v3) {
          if (v < v1) {
            if (v < v0) { v3 = v2; i3 = i2; v2 = v1; i2 = i1; v1 = v0; i1 = i0; v0 = v; i0 = id; }
            else { v3 = v2; i3 = i2; v2 = v1; i2 = i1; v1 = v; i1 = id; }
          } else {
            if (v < v2) { v3 = v2; i3 = i2; v2 = v; i2 = id; }
            else { v3 = v; i3 = id; }
          }
        }
      }
    }
    lv[tid * 4] = v0; li[tid * 4] = i0;
    lv[tid * 4 + 1] = v1; li[tid * 4 + 1] = i1;
    lv[tid * 4 + 2] = v2; li[tid * 4 + 2] = i2;
    lv[tid * 4 + 3] = v3; li[tid * 4 + 3] = i3;
  }
  __syncthreads();
  // phase 2: 32 threads, each scans 32 -> top-8
  if (tid < 32) {
    float bv[8]; int bi[8];
    for (int k = 0; k < 8; ++k) { bv[k] = INF_F; bi[k] = 0x7fffffff; }
    for (int p = 0; p < 32; ++p) insert_sorted(bv, bi, 8, lv[tid * 32 + p], li[tid * 32 + p]);
    for (int k = 0; k < 8; ++k) { l2v[tid * 8 + k] = bv[k]; l2i[tid * 8 + k] = bi[k]; }
  }
  __syncthreads();
  // phase 3: one thread, 256 -> top-16
  if (tid == 0) {
    float bv[16]; int bi[16];
    for (int k = 0; k < 16; ++k) { bv[k] = INF_F; bi[k] = 0x7fffffff; }
    for (int p = 0; p < 256; ++p) insert_sorted(bv, bi, 16, l2v[p], l2i[p]);
    for (int k = 0; k < 16; ++k) sel[k] = bi[k];
  }
  // q_sq in fp64
  double qp = 0.0;
  for (int dd = tid; dd < DIM; dd += 256) {
    double x = (double)query[(size_t)q * DIM + dd];
    qp += x * x;
  }
#pragma unroll
  for (int off = 32; off > 0; off >>= 1) qp += __shfl_down(qp, off);
  if (lane == 0) qred[wave] = qp;
  __syncthreads();
  if (tid == 0) qsq_sh = qred[0] + qred[1] + qred[2] + qred[3];
  __syncthreads();
  // rescore 16 candidates in fp64 (wave per candidate, 4 rounds)
  for (int cnum = wave; cnum < 16; cnum += 4) {
    int n = sel[cnum];
    const float* xr = lib + (size_t)n * DIM;
    const float* qr = query + (size_t)q * DIM;
    double dot = 0.0, xs = 0.0;
#pragma unroll
    for (int c4 = 0; c4 < 3; ++c4) {
      f32x4 xv = *(const f32x4*)(xr + lane * 12 + c4 * 4);
      f32x4 qv = *(const f32x4*)(qr + lane * 12 + c4 * 4);
#pragma unroll
      for (int e = 0; e < 4; ++e) {
        dot += (double)qv[e] * (double)xv[e];
        xs += (double)xv[e] * (double)xv[e];
      }
    }
#pragma unroll
    for (int off = 32; off > 0; off >>= 1) {
      dot += __shfl_down(dot, off);
      xs += __shfl_down(xs, off);
    }
    if (lane == 0) d2_sh[cnum] = qsq_sh - 2.0 * dot + xs;
  }
  __syncthreads();
  // final: sort 16 by (d2, idx) ascending, emit 10
  if (tid == 0) {
    double dv[16]; int di[16];
    for (int k = 0; k < 16; ++k) { dv[k] = d2_sh[k]; di[k] = sel[k]; }
    for (int a = 0; a < 10; ++a) {
      int best = a;
      for (int b = a + 1; b < 16; ++b)
        if (dv[b] < dv[best] || (dv[b] == dv[best] && di[b] < di[best])) best = b;
      double tv = dv[a]; dv[a] = dv[best]; dv[best] = tv;
      int ti = di[a]; di[a] = di[best]; di[best] = ti;
    }
    for (int j = 0; j < 10; ++j) {
      out[q * 10 + j] = (float)dv[j];
      out[QN * 10 + q * 10 + j] = (float)di[j];
    }
  }
}

// ---------------------------------------------------------------------------
extern "C" void kernel_launch(void* const* d_in, const int* in_sizes, int n_in,
                              void* d_out, int out_size, void* d_ws,
                              size_t ws_size, hipStream_t stream) {
  (void)in_sizes; (void)n_in; (void)out_size; (void)ws_size;
  const float* query = (const float*)d_in[0];
  const float* lib = (const float*)d_in[1];
  char* ws = (char*)d_ws;
  _Float16* A_ws = (_Float16*)ws;                                  // 768 KB
  float* cand_val = (float*)(ws + (1u << 20));                     // 16 MB
  int* cand_idx = (int*)(ws + (1u << 20) + (size_t)NBLOCKS * QN * 4 * 4);
  float* out = (float*)d_out;

  prep_A<<<192, 256, 0, stream>>>(query, A_ws);
  gemm_select<<<NBLOCKS, 512, 0, stream>>>(lib, A_ws, cand_val, cand_idx);
  merge_rescore<<<QN, 256, 0, stream>>>(query, lib, cand_val, cand_idx, out);
}